// Round 9
// baseline (25.032 us; speedup 1.0000x reference)
//
#include <hip/hip_runtime.h>

#define NUM_EMBEDDINGS 50000
#define EMBEDDING_DIM  1024
#define N_CENTROIDS    256
#define N_BLOCKS       128   // EMBEDDING_DIM / 8
#define N_TOKENS       16384 // BATCH * SEQ

typedef float f32x4 __attribute__((ext_vector_type(4)));

// ---------------- Kernel 1: transpose + narrow the code table ----------------
// (verbatim from R2 — validated absmax=0 there)
// in : assign [N_BLOCKS][NUM_EMBEDDINGS] int32 (values 0..255)
// out: codes8 [NUM_EMBEDDINGS][N_BLOCKS] uint8  (one 128 B line per embedding id)
// Steady state: reads are per-XCD L2-resident (3.2 MB slice per XCD since
// block g -> XCD g%8 reads every 8th 64-id tile), writes 6.4 MB.
__global__ __launch_bounds__(256) void transpose_codes_kernel(
    const int* __restrict__ assign,
    unsigned char* __restrict__ codes8)
{
    __shared__ int tile[N_BLOCKS][65];

    const int t = threadIdx.x;
    const int id_base = blockIdx.x * 64;

    const int blk_r = t >> 4;   // 0..15
    const int idq   = t & 15;   // int4 column 0..15
    #pragma unroll
    for (int it = 0; it < 8; ++it) {
        const int blk = it * 16 + blk_r;
        const int id  = id_base + idq * 4;
        if (id + 3 < NUM_EMBEDDINGS) {
            const int4 v = *reinterpret_cast<const int4*>(&assign[blk * NUM_EMBEDDINGS + id]);
            tile[blk][idq * 4 + 0] = v.x;
            tile[blk][idq * 4 + 1] = v.y;
            tile[blk][idq * 4 + 2] = v.z;
            tile[blk][idq * 4 + 3] = v.w;
        }
    }
    __syncthreads();

    const int c4      = t & 31;  // uchar4 column
    const int id_part = t >> 5;  // 0..7
    #pragma unroll
    for (int it = 0; it < 8; ++it) {
        const int id_l = it * 8 + id_part;
        const int id_g = id_base + id_l;
        if (id_g < NUM_EMBEDDINGS) {
            const unsigned int b0 = (unsigned int)tile[c4 * 4 + 0][id_l] & 0xFFu;
            const unsigned int b1 = (unsigned int)tile[c4 * 4 + 1][id_l] & 0xFFu;
            const unsigned int b2 = (unsigned int)tile[c4 * 4 + 2][id_l] & 0xFFu;
            const unsigned int b3 = (unsigned int)tile[c4 * 4 + 3][id_l] & 0xFFu;
            reinterpret_cast<unsigned int*>(codes8)[id_g * (N_BLOCKS / 4) + c4] =
                b0 | (b1 << 8) | (b2 << 16) | (b3 << 24);
        }
    }
}

// ---------------- Kernel 2: gather with coalesced code reads + nt stores ----
// One 256-thread block per token.
//   codes: block reads 128 B (2 lines) total — 2 L2 requests per token
//          vs 128 scattered 200 KB-strided requests in the R5 family.
//   store: thread t writes float4 #t -> 4 KB fully contiguous per block, nt
//          (keeps transpose's assignment slices + codes8 rows L2-resident).
__global__ __launch_bounds__(256) void pq_gather_nt_kernel(
    const float* __restrict__ centroids,          // [256][8]
    const unsigned char* __restrict__ codes8,     // [50000][128]
    const int* __restrict__ input_ids,            // [16384]
    float* __restrict__ out)                      // [16384][1024]
{
    const int token = blockIdx.x;
    const int tid   = threadIdx.x;

    const int id   = input_ids[token];
    const int code = codes8[id * N_BLOCKS + (tid >> 1)];

    const f32x4 v = reinterpret_cast<const f32x4*>(centroids)[(code << 1) + (tid & 1)];

    f32x4* dst = reinterpret_cast<f32x4*>(out) + (size_t)token * (EMBEDDING_DIM / 4) + tid;
    __builtin_nontemporal_store(v, dst);
}

// ---------------- Fallback (R5 kernel) if ws is too small ----------------
__global__ __launch_bounds__(256) void pq_embed_xcd_nt_kernel(
    const float* __restrict__ centroids,
    const int*   __restrict__ assignments,
    const int*   __restrict__ input_ids,
    float*       __restrict__ out)
{
    const int part  = blockIdx.x & 7;
    const int group = blockIdx.x >> 3;
    const int tid   = threadIdx.x;
    const int tgrp  = tid >> 5;
    const int lane  = tid & 31;

    const int token = group * 8 + tgrp;
    const int id    = input_ids[token];
    const int blk   = part * 16 + (lane >> 1);
    const int half  = lane & 1;

    const int code = assignments[blk * NUM_EMBEDDINGS + id];
    const f32x4 v  = reinterpret_cast<const f32x4*>(centroids)[(code << 1) + half];

    f32x4* dst = reinterpret_cast<f32x4*>(out) +
                 (size_t)token * (EMBEDDING_DIM / 4) + part * 32 + lane;
    __builtin_nontemporal_store(v, dst);
}

extern "C" void kernel_launch(void* const* d_in, const int* in_sizes, int n_in,
                              void* d_out, int out_size, void* d_ws, size_t ws_size,
                              hipStream_t stream) {
    const float* centroids   = (const float*)d_in[0];
    const int*   assignments = (const int*)d_in[1];
    const int*   input_ids   = (const int*)d_in[2];
    float*       out         = (float*)d_out;

    const size_t ws_needed = (size_t)NUM_EMBEDDINGS * N_BLOCKS;  // 6.4 MB
    if (ws_size >= ws_needed) {
        unsigned char* codes8 = (unsigned char*)d_ws;
        const int n_tiles = (NUM_EMBEDDINGS + 63) / 64;  // 782
        transpose_codes_kernel<<<n_tiles, 256, 0, stream>>>(assignments, codes8);
        pq_gather_nt_kernel<<<N_TOKENS, 256, 0, stream>>>(centroids, codes8, input_ids, out);
    } else {
        pq_embed_xcd_nt_kernel<<<N_TOKENS / 8 * 8, 256, 0, stream>>>(centroids, assignments, input_ids, out);
    }
}